// Round 10
// baseline (347.917 us; speedup 1.0000x reference)
//
#include <hip/hip_runtime.h>
#include <hip/hip_bf16.h>

typedef __attribute__((ext_vector_type(8))) short bf16x8;
typedef __attribute__((ext_vector_type(8))) unsigned short ushort8;
typedef __attribute__((ext_vector_type(4))) float f32x4;
typedef unsigned int u32;

#define D_DIM 512
#define C_DIM 1024
#define B_DIM 65536

__device__ __forceinline__ unsigned short f2bf(float x) {
  u32 u = __float_as_uint(x);
  u32 r = (u + 0x7fffu + ((u >> 16) & 1u)) >> 16;
  return (unsigned short)r;
}

__device__ __forceinline__ void async16(const void* g, void* l) {
  __builtin_amdgcn_global_load_lds(
      (const __attribute__((address_space(1))) u32*)g,
      (__attribute__((address_space(3))) u32*)l, 16, 0, 0);
}

// sharp(x) = sigmoid(10x-5) + sigmoid(-10x-5)
//          = (E t^2 + 2t + 1) / (E t^2 + (1+E) t + 1),  t = e^(10x-5), E = e^10.
__device__ __forceinline__ float sharpf(float x) {
  float t = __expf(10.f * x - 5.f);
  float u = 22026.4658f * t * t;
  float num = u + 2.f * t + 1.f;
  float den = u + 22027.4658f * t + 1.f;
  return num * __builtin_amdgcn_rcpf(den);
}

// Normalize rows of length 512 (l2, +1e-12 eps) and cast to bf16.
__global__ __launch_bounds__(256) void rownorm_kernel(
    const float* __restrict__ src, unsigned short* __restrict__ dst) {
  int row = blockIdx.x * 4 + (threadIdx.x >> 6);
  int lane = threadIdx.x & 63;
  const float* s = src + (size_t)row * D_DIM + lane * 8;
  float4 v0 = *(const float4*)s;
  float4 v1 = *(const float4*)(s + 4);
  float ss = v0.x * v0.x + v0.y * v0.y + v0.z * v0.z + v0.w * v0.w +
             v1.x * v1.x + v1.y * v1.y + v1.z * v1.z + v1.w * v1.w;
#pragma unroll
  for (int m = 32; m >= 1; m >>= 1) ss += __shfl_xor(ss, m);
  float rinv = rsqrtf(ss + 1e-12f);
  float tv[8] = {v0.x, v0.y, v0.z, v0.w, v1.x, v1.y, v1.z, v1.w};
  ushort8 o;
#pragma unroll
  for (int i = 0; i < 8; ++i) o[i] = f2bf(tv[i] * rinv);
  *(ushort8*)(dst + (size_t)row * D_DIM + lane * 8) = o;
}

// vbT[n][k] = bf16(val[k][n])  (transpose+cast, 32x32 LDS tiles)
__global__ __launch_bounds__(256) void valT_kernel(
    const float* __restrict__ val, unsigned short* __restrict__ vbT) {
  __shared__ float tile[32][33];
  int bx = blockIdx.x & 31;  // n tile
  int by = blockIdx.x >> 5;  // k tile
  int t = threadIdx.x;
  int r = t >> 5, c = t & 31;
#pragma unroll
  for (int i = 0; i < 4; ++i)
    tile[r + i * 8][c] = val[(size_t)(by * 32 + r + i * 8) * C_DIM + bx * 32 + c];
  __syncthreads();
#pragma unroll
  for (int i = 0; i < 4; ++i)
    vbT[(size_t)(bx * 32 + r + i * 8) * C_DIM + by * 32 + c] = f2bf(tile[c][r + i * 8]);
}

// rsum[i] = sum of the 8 per-n-block partials
__global__ __launch_bounds__(256) void rsum_reduce_kernel(
    const float* __restrict__ part, float* __restrict__ rsum) {
  int i = blockIdx.x * 256 + threadIdx.x;
  float v = 0.f;
#pragma unroll
  for (int j = 0; j < 8; ++j) v += part[i + (size_t)j * B_DIM];
  rsum[i] = v;
}

// 128x128 GEMM tile, BK=32, 256 thr = 4 waves (2Mx2N), per-wave 64x64
// (4x4 16x16x32 frags, acc 64 f32 -> fits 4 waves/SIMD => 4 blocks/CU with
// 32KB LDS). r7-style staggered counted-vmcnt schedule, 2 phases/tile:
//  head: vmcnt(3) [tile T's 4 loads retire; T+1's u0 (3) stays in flight]
//        (vmcnt(0) at last tile); s_barrier.
//  ph0: reads A mf0,1 + ALL B; stage_u1(T+1) [other buffer, safe after
//       head-BAR]; setprio MFMA quad 0.
//  ph1: reads A mf2,3; BAR; stage_u0(T+2) [current buffer, rows whose
//       readers all retired before this BAR]; setprio MFMA quad 1.
// u0 = A bands [0,32)+[64,96) + all B (3 loads/thr); u1 = A bands
// [32,64)+[96,128) (1 load/thr). Prologue: u0(0),u1(0),u0(1) = 7 loads.
// LDS swizzle for 64B rows: col ^= ((r>>1)&3)<<3 (u16) — within any 16-lane
// b128 group: 8 distinct 16B slots x 2 lanes = conflict-free. Stage uses
// inverse-swizzled global source + linear LDS dest (both-sides rule).
// SHARP epilogue: sharp -> swizzled LDS scatter (col ^ ((rl>>2)&3)<<4) ->
// coalesced 16B w store -> wc-reduce rowsums -> rsum_part[n][row] (no
// atomics; partials live in d_out scratch).  !SHARP: scale by rcp(rsum), f32.
template <int K, bool SHARP>
__global__ __launch_bounds__(256, 4) void gemm128_kernel(
    const unsigned short* __restrict__ A, const unsigned short* __restrict__ Bm,
    unsigned short* __restrict__ wout, float* __restrict__ rsum,
    float* __restrict__ fout) {
  __shared__ unsigned short smem[16384];  // 32 KB
  const int NKT = K / 32;
  const int bid = blockIdx.x;
  // XCD-chunked bijective swizzle: nwg=4096, 8 XCDs, 512 per chunk.
  const int wg = (bid & 7) * 512 + (bid >> 3);
  const int m0 = (wg >> 3) * 128;
  const int n0 = (wg & 7) * 128;
  const int t = threadIdx.x;
  const int lane = t & 63;
  const int wv = t >> 6;
  const int wr = wv >> 1;  // 0..1
  const int wc = wv & 1;   // 0..1
  const int lo = lane & 15, hi = lane >> 4;

  const int rl4 = t >> 2;       // 0..63
  const int sc = (t & 3) * 8;   // 16B slot base within 32-u16 row
  auto stage_u0 = [&](int T) {  // A bands [0,32)+[64,96) + all B: 3 loads
    const int d = (T & 1) * 8192;
    {
      int r = (rl4 >> 5) * 64 + (rl4 & 31);
      int cl = sc ^ (((r >> 1) & 3) << 3);
      async16(A + (size_t)(m0 + r) * K + (size_t)T * 32 + cl,
              &smem[d + r * 32 + sc]);
    }
#pragma unroll
    for (int i = 0; i < 2; ++i) {
      int s = i * 256 + t;
      int r = s >> 2, c = (s & 3) * 8;
      int cl = c ^ (((r >> 1) & 3) << 3);
      async16(Bm + (size_t)(n0 + r) * K + (size_t)T * 32 + cl,
              &smem[d + 4096 + r * 32 + c]);
    }
  };
  auto stage_u1 = [&](int T) {  // A bands [32,64)+[96,128): 1 load
    const int d = (T & 1) * 8192;
    int r = (rl4 >> 5) * 64 + 32 + (rl4 & 31);
    int cl = sc ^ (((r >> 1) & 3) << 3);
    async16(A + (size_t)(m0 + r) * K + (size_t)T * 32 + cl,
            &smem[d + r * 32 + sc]);
  };

  f32x4 acc[4][4];
#pragma unroll
  for (int i = 0; i < 4; ++i)
#pragma unroll
    for (int j = 0; j < 4; ++j) acc[i][j] = (f32x4){0.f, 0.f, 0.f, 0.f};

  stage_u0(0); stage_u1(0); stage_u0(1);  // 7 loads in flight

#pragma unroll 1
  for (int T = 0; T < NKT; ++T) {
    if (T == NKT - 1) {
      asm volatile("s_waitcnt vmcnt(0)" ::: "memory");
    } else {
      asm volatile("s_waitcnt vmcnt(3)" ::: "memory");
    }
    __builtin_amdgcn_s_barrier();
    const int d = (T & 1) * 8192;
    bf16x8 bfr[4];
    {  // phase 0
      bf16x8 af[2];
#pragma unroll
      for (int mi = 0; mi < 2; ++mi) {
        int r = wr * 64 + mi * 16 + lo;
        af[mi] = *(const bf16x8*)&smem[d + r * 32 + ((hi * 8) ^ (((r >> 1) & 3) << 3))];
      }
#pragma unroll
      for (int nf = 0; nf < 4; ++nf) {
        int r = wc * 64 + nf * 16 + lo;
        bfr[nf] =
            *(const bf16x8*)&smem[d + 4096 + r * 32 + ((hi * 8) ^ (((r >> 1) & 3) << 3))];
      }
      if (T + 1 < NKT) stage_u1(T + 1);
      __builtin_amdgcn_s_setprio(1);
#pragma unroll
      for (int mi = 0; mi < 2; ++mi)
#pragma unroll
        for (int nf = 0; nf < 4; ++nf)
          acc[mi][nf] = __builtin_amdgcn_mfma_f32_16x16x32_bf16(
              af[mi], bfr[nf], acc[mi][nf], 0, 0, 0);
      __builtin_amdgcn_s_setprio(0);
    }
    {  // phase 1
      bf16x8 af[2];
#pragma unroll
      for (int mi = 0; mi < 2; ++mi) {
        int r = wr * 64 + (2 + mi) * 16 + lo;
        af[mi] = *(const bf16x8*)&smem[d + r * 32 + ((hi * 8) ^ (((r >> 1) & 3) << 3))];
      }
      __builtin_amdgcn_s_barrier();
      if (T + 2 < NKT) stage_u0(T + 2);
      __builtin_amdgcn_s_setprio(1);
#pragma unroll
      for (int mi = 0; mi < 2; ++mi)
#pragma unroll
        for (int nf = 0; nf < 4; ++nf)
          acc[2 + mi][nf] = __builtin_amdgcn_mfma_f32_16x16x32_bf16(
              af[mi], bfr[nf], acc[2 + mi][nf], 0, 0, 0);
      __builtin_amdgcn_s_setprio(0);
    }
  }
  __syncthreads();  // all reads done; nothing outstanding (last head vmcnt 0)

  if (SHARP) {
    float rs[4][4];
#pragma unroll
    for (int i = 0; i < 4; ++i)
#pragma unroll
      for (int j = 0; j < 4; ++j) rs[i][j] = 0.f;
    unsigned short* ep = smem;  // 128x128 u16 = 32 KB
#pragma unroll
    for (int mf = 0; mf < 4; ++mf)
#pragma unroll
      for (int nf = 0; nf < 4; ++nf)
#pragma unroll
        for (int j = 0; j < 4; ++j) {
          float s = sharpf(acc[mf][nf][j]);
          rs[mf][j] += s;
          int rl = wr * 64 + mf * 16 + (hi << 2) + j;
          int cl = (wc * 64 + nf * 16 + lo) ^ (((rl >> 2) & 3) << 4);
          ep[rl * 128 + cl] = f2bf(s);
        }
    // reduce rs over the 16 lo-lanes (butterfly)
#pragma unroll
    for (int mf = 0; mf < 4; ++mf)
#pragma unroll
      for (int j = 0; j < 4; ++j) {
        float v = rs[mf][j];
        v += __shfl_xor(v, 1);
        v += __shfl_xor(v, 2);
        v += __shfl_xor(v, 4);
        v += __shfl_xor(v, 8);
        rs[mf][j] = v;
      }
    __syncthreads();
    // coalesced 16B/lane store of the 128x128 tile (un-swizzle on read)
#pragma unroll
    for (int pass = 0; pass < 8; ++pass) {
      int idx = pass * 2048 + t * 8;
      int row = idx >> 7, col = idx & 127;
      int phys = row * 128 + (col ^ (((row >> 2) & 3) << 4));
      *(ushort8*)&wout[(size_t)(m0 + row) * C_DIM + n0 + col] =
          *(const ushort8*)&ep[phys];
    }
    __syncthreads();
    // wc-reduction of row sums via 1 KB of LDS, then plain global store
    float* rbuf = (float*)smem;  // [2][128]
    if (lo == 0) {
#pragma unroll
      for (int mf = 0; mf < 4; ++mf)
#pragma unroll
        for (int j = 0; j < 4; ++j)
          rbuf[wc * 128 + wr * 64 + mf * 16 + (hi << 2) + j] = rs[mf][j];
    }
    __syncthreads();
    if (t < 128) {
      rsum[(size_t)(wg & 7) * B_DIM + m0 + t] = rbuf[t] + rbuf[128 + t];
    }
  } else {
    float rinv[4][4];
#pragma unroll
    for (int mf = 0; mf < 4; ++mf) {
      float4 r4 = *(const float4*)&rsum[m0 + wr * 64 + mf * 16 + (hi << 2)];
      rinv[mf][0] = __builtin_amdgcn_rcpf(r4.x);
      rinv[mf][1] = __builtin_amdgcn_rcpf(r4.y);
      rinv[mf][2] = __builtin_amdgcn_rcpf(r4.z);
      rinv[mf][3] = __builtin_amdgcn_rcpf(r4.w);
    }
#pragma unroll
    for (int mf = 0; mf < 4; ++mf)
#pragma unroll
      for (int nf = 0; nf < 4; ++nf)
#pragma unroll
        for (int j = 0; j < 4; ++j)
          fout[(size_t)(m0 + wr * 64 + mf * 16 + (hi << 2) + j) * C_DIM +
               n0 + wc * 64 + nf * 16 + lo] = acc[mf][nf][j] * rinv[mf][j];
  }
}

extern "C" void kernel_launch(void* const* d_in, const int* in_sizes, int n_in,
                              void* d_out, int out_size, void* d_ws, size_t ws_size,
                              hipStream_t stream) {
  const float* query = (const float*)d_in[0];
  const float* key = (const float*)d_in[1];
  const float* val = (const float*)d_in[2];
  float* out = (float*)d_out;
  const int B = in_sizes[0] / D_DIM;  // 65536

  char* ws = (char*)d_ws;
  unsigned short* kb = (unsigned short*)(ws);                         // 1 MB
  unsigned short* vbT = (unsigned short*)(ws + (1ull << 20));         // 2 MB
  unsigned short* qb = (unsigned short*)(ws + 4ull * (1ull << 20));   // 64 MB
  float* rsum = (float*)qb;           // reuses qb region (dead after GEMM1)
  float* rsum_part = (float*)d_out;   // 2 MB scratch in out (dead until GEMM2)
  unsigned short* wbf = (unsigned short*)(ws + 68ull * (1ull << 20)); // 128 MB

  rownorm_kernel<<<dim3(B / 4), dim3(256), 0, stream>>>(query, qb);
  rownorm_kernel<<<dim3(C_DIM / 4), dim3(256), 0, stream>>>(key, kb);
  valT_kernel<<<dim3(1024), dim3(256), 0, stream>>>(val, vbT);

  dim3 grid((B / 128) * (C_DIM / 128));  // 4096 blocks
  gemm128_kernel<D_DIM, true><<<grid, dim3(256), 0, stream>>>(qb, kb, wbf, rsum_part, nullptr);
  rsum_reduce_kernel<<<dim3(B / 256), dim3(256), 0, stream>>>(rsum_part, rsum);
  gemm128_kernel<C_DIM, false><<<grid, dim3(256), 0, stream>>>(wbf, vbT, nullptr, rsum, out);
}